// Round 7
// baseline (314.382 us; speedup 1.0000x reference)
//
#include <hip/hip_runtime.h>
#include <hip/hip_bf16.h>

#define NPTS  20000
#define DIM   128
#define NA    1024
#define NTASK 2048
#define G     8        // tasks per dist block
#define P     4        // points per thread (wave-strided)
#define TILE  1024     // points per dist block
#define KSEL  50
#define GAMMA 1.0f
#define CCAP  2048     // candidate capacity per task
#define RRANK 12       // sample rank used as threshold (of 512 samples)

typedef unsigned char  u8t;
typedef unsigned short u16t;

static __device__ __forceinline__ unsigned sad8(unsigned a, unsigned b, unsigned c) {
#if __has_builtin(__builtin_amdgcn_sad_u8)
    return __builtin_amdgcn_sad_u8(a, b, c);
#else
    unsigned d;
    asm("v_sad_u8 %0, %1, %2, %3" : "=v"(d) : "v"(a), "v"(b), "v"(c));
    return d;
#endif
}

__global__ __launch_bounds__(256) void init_kernel(float* out, unsigned* gcnt, unsigned* gmax) {
    const int i = (int)blockIdx.x * 256 + (int)threadIdx.x;
    if (i < NTASK) gcnt[i] = 0u;
    if (i == 0) { out[0] = 0.0f; gmax[0] = 0u; }
}

__global__ __launch_bounds__(256) void maxabs_kernel(
    const float* __restrict__ o1, const float* __restrict__ o2,
    unsigned* __restrict__ gmax)
{
    const int nt = (int)gridDim.x * 256;
    const float4* a = (const float4*)o1;
    const float4* b = (const float4*)o2;
    float m = 0.0f;
    for (int i = (int)blockIdx.x * 256 + (int)threadIdx.x; i < NPTS * DIM / 4; i += nt) {
        const float4 x = a[i], y = b[i];
        m = fmaxf(m, fmaxf(fmaxf(fabsf(x.x), fabsf(x.y)), fmaxf(fabsf(x.z), fabsf(x.w))));
        m = fmaxf(m, fmaxf(fmaxf(fabsf(y.x), fabsf(y.y)), fmaxf(fabsf(y.z), fabsf(y.w))));
    }
    #pragma unroll
    for (int off = 32; off >= 1; off >>= 1) m = fmaxf(m, __shfl_xor(m, off));
    if ((threadIdx.x & 63) == 0) atomicMax(gmax, __float_as_uint(m));  // m >= 0: bit order == float order
}

static __device__ __forceinline__ unsigned q4(const float4 v, const float M, const float s) {
    unsigned u0 = __float2uint_rn((v.x + M) * s); if (u0 > 255u) u0 = 255u;
    unsigned u1 = __float2uint_rn((v.y + M) * s); if (u1 > 255u) u1 = 255u;
    unsigned u2 = __float2uint_rn((v.z + M) * s); if (u2 > 255u) u2 = 255u;
    unsigned u3 = __float2uint_rn((v.w + M) * s); if (u3 > 255u) u3 = 255u;
    return u0 | (u1 << 8) | (u2 << 16) | (u3 << 24);
}

// Transpose-packed planes, fully coalesced both sides: lanes 0..7 cover one
// row contiguously (cq fastest), so a wave reads 8 whole rows back-to-back.
__global__ __launch_bounds__(256) void quant_pack_kernel(
    const float* __restrict__ o1, const float* __restrict__ o2,
    uint4* __restrict__ qp1, uint4* __restrict__ qp2,
    const unsigned* __restrict__ gmax)
{
    const float M = __uint_as_float(*gmax);
    const float s = 255.0f / (2.0f * M);
    const int idx = (int)blockIdx.x * 256 + (int)threadIdx.x;   // 1250*256 == 2*NPTS*8
    const int m  = idx / (NPTS * 8);
    const int r  = idx - m * (NPTS * 8);
    const int n  = r >> 3;
    const int cq = r & 7;
    const float4* src = (const float4*)((m ? o2 : o1) + (size_t)n * DIM + cq * 16);
    uint4 o;
    o.x = q4(src[0], M, s);
    o.y = q4(src[1], M, s);
    o.z = q4(src[2], M, s);
    o.w = q4(src[3], M, s);
    (m ? qp2 : qp1)[(size_t)cq * NPTS + n] = o;
}

// Gather + quantize anchor rows: astage[cq*NTASK + t].
__global__ __launch_bounds__(256) void astage_kernel(
    const float* __restrict__ o1, const float* __restrict__ o2,
    const int* __restrict__ anchor1, const int* __restrict__ anchor2,
    uint4* __restrict__ astage, const unsigned* __restrict__ gmax)
{
    const float M = __uint_as_float(*gmax);
    const float s = 255.0f / (2.0f * M);
    const int idx = (int)blockIdx.x * 256 + (int)threadIdx.x;
    if (idx >= NTASK * 8) return;
    const int t = idx >> 3, cq = idx & 7;
    int row; const float* src;
    if (t < NA) { row = anchor1[t];      src = o1; }
    else        { row = anchor2[t - NA]; src = o2; }
    const float4* rp = (const float4*)(src + (size_t)row * DIM + cq * 16);
    uint4 o;
    o.x = q4(rp[0], M, s);
    o.y = q4(rp[1], M, s);
    o.z = q4(rp[2], M, s);
    o.w = q4(rp[3], M, s);
    astage[(size_t)cq * NTASK + t] = o;
}

// Per-task threshold: exact rank-RRANK distance among 512 fixed sample points
// (8 coalesced runs of 64; the same 64KB of planes for every block -> L2-hot).
__global__ __launch_bounds__(256) void sample_kernel(
    const uint4* __restrict__ qp1, const uint4* __restrict__ qp2,
    const uint4* __restrict__ astage, unsigned* __restrict__ tau)
{
    __shared__ u16t sd[512];
    __shared__ unsigned h[256];
    __shared__ unsigned s_b0, s_r1;

    const int tid = threadIdx.x;
    const int t = (int)blockIdx.x;
    const uint4* qp = (t < NA) ? qp2 : qp1;

    uint4 A[8];
    #pragma unroll
    for (int cq = 0; cq < 8; ++cq) A[cq] = astage[(size_t)cq * NTASK + t];

    for (int s = tid; s < 512; s += 256) {
        const int rr = s >> 6;
        const int n = rr * 2500 + (s & 63);
        unsigned acc = 0;
        #pragma unroll
        for (int cq = 0; cq < 8; ++cq) {
            const uint4 pv = qp[(size_t)cq * NPTS + n];
            acc = sad8(pv.x, A[cq].x, acc);
            acc = sad8(pv.y, A[cq].y, acc);
            acc = sad8(pv.z, A[cq].z, acc);
            acc = sad8(pv.w, A[cq].w, acc);
        }
        sd[s] = (u16t)acc;
    }
    h[tid] = 0u;
    __syncthreads();
    for (int s = tid; s < 512; s += 256) atomicAdd(&h[sd[s] >> 8], 1u);
    __syncthreads();
    if (tid == 0) {
        unsigned cum = 0, b = 0;
        for (;; ++b) { const unsigned c = h[b]; if (cum + c >= RRANK) break; cum += c; }
        s_b0 = b; s_r1 = RRANK - cum;
    }
    __syncthreads();
    const unsigned b0 = s_b0, r1 = s_r1;
    __syncthreads();
    h[tid] = 0u;
    __syncthreads();
    for (int s = tid; s < 512; s += 256)
        if ((unsigned)(sd[s] >> 8) == b0) atomicAdd(&h[sd[s] & 255u], 1u);
    __syncthreads();
    if (tid == 0) {
        unsigned rem = r1, b = 0;
        for (;; ++b) { const unsigned c = h[b]; if (c >= rem) break; rem -= c; }
        tau[t] = (b0 << 8) | b;
    }
}

// Main SAD pass: no distance-matrix store, no min-reduce -- emits only
// candidates with d <= tau[t] (~470/task) via per-lane atomicAdd on the
// per-task counter (2048 distinct addresses, negligible contention).
__global__ __launch_bounds__(256) void dist_kernel(
    const uint4* __restrict__ qp1, const uint4* __restrict__ qp2,
    const uint4* __restrict__ astage, const unsigned* __restrict__ tau,
    u16t* __restrict__ cand, unsigned* __restrict__ gcnt)
{
    const int tid = threadIdx.x;
    const int t0 = (int)blockIdx.x * G;
    const uint4* qp = (t0 < NA) ? qp2 : qp1;

    const int w = tid >> 6, l = tid & 63;
    const int nbase = (int)blockIdx.y * TILE + w * 256 + l;   // point p: nbase + p*64

    unsigned tg[G];
    #pragma unroll
    for (int g = 0; g < G; ++g) tg[g] = tau[t0 + g];          // uniform -> s_load

    unsigned acc[P][G];
    #pragma unroll
    for (int p = 0; p < P; ++p)
        #pragma unroll
        for (int g = 0; g < G; ++g) acc[p][g] = 0u;

    #pragma unroll
    for (int cq = 0; cq < 8; ++cq) {
        uint4 A[G];
        #pragma unroll
        for (int g = 0; g < G; ++g) A[g] = astage[(size_t)cq * NTASK + t0 + g];
        uint4 pv[P];
        #pragma unroll
        for (int p = 0; p < P; ++p) {
            int n = nbase + p * 64;
            n = n < NPTS ? n : NPTS - 1;       // clamped load; emission predicated
            pv[p] = qp[(size_t)cq * NPTS + n];
        }
        #pragma unroll
        for (int g = 0; g < G; ++g) {
            #pragma unroll
            for (int p = 0; p < P; ++p) {
                unsigned a = acc[p][g];
                a = sad8(pv[p].x, A[g].x, a);
                a = sad8(pv[p].y, A[g].y, a);
                a = sad8(pv[p].z, A[g].z, a);
                a = sad8(pv[p].w, A[g].w, a);
                acc[p][g] = a;
            }
        }
    }

    #pragma unroll
    for (int g = 0; g < G; ++g) {
        #pragma unroll
        for (int p = 0; p < P; ++p) {
            const int n = nbase + p * 64;
            if (n < NPTS && acc[p][g] <= tg[g]) {
                const unsigned pos = atomicAdd(&gcnt[t0 + g], 1u);
                if (pos < CCAP) cand[(size_t)(t0 + g) * CCAP + pos] = (u16t)acc[p][g];
            }
        }
    }
}

// One block per task: exact top-K loss from the candidate list (top-50 is a
// subset whenever cnt >= KSEL). Fallback (cnt < KSEL or list overflow):
// recompute the full row into LDS and select there -- rare but exact.
__global__ __launch_bounds__(256) void finish_kernel(
    const float* __restrict__ o1, const float* __restrict__ o2,
    const int* __restrict__ anchor1, const int* __restrict__ anchor2,
    const uint4* __restrict__ qp1, const uint4* __restrict__ qp2,
    const uint4* __restrict__ astage,
    const u16t* __restrict__ cand, const unsigned* __restrict__ gcnt,
    const unsigned* __restrict__ gmax, float* __restrict__ d_out)
{
    __shared__ u16t sd[NPTS];            // 40 KB (fallback row; fast path uses a prefix)
    __shared__ float red[256];
    __shared__ unsigned h[256];
    __shared__ unsigned s_b0, s_r1, s_kth, s_remf;

    const int tid = threadIdx.x;
    const int t = (int)blockIdx.x;

    // D = pos + GAMMA (exact fp32 from originals)
    const int a = (t < NA) ? t : (t - NA);
    const int i1 = anchor1[a], i2 = anchor2[a];
    float p = 0.0f;
    if (tid < DIM) p = fabsf(o1[(size_t)i1 * DIM + tid] - o2[(size_t)i2 * DIM + tid]);
    red[tid] = p;
    __syncthreads();
    for (int s = 128; s >= 1; s >>= 1) { if (tid < s) red[tid] += red[tid + s]; __syncthreads(); }
    const float D = red[0] + GAMMA;
    __syncthreads();

    const float M = __uint_as_float(*gmax);
    const float dq = 2.0f * M / 255.0f;
    const unsigned cnt = gcnt[t];

    int L;
    if (cnt >= KSEL && cnt <= CCAP) {
        for (int i = tid; i < (int)cnt; i += 256) sd[i] = cand[(size_t)t * CCAP + i];
        L = (int)cnt;
    } else {
        const uint4* qp = (t < NA) ? qp2 : qp1;
        uint4 A[8];
        #pragma unroll
        for (int cq = 0; cq < 8; ++cq) A[cq] = astage[(size_t)cq * NTASK + t];
        for (int n = tid; n < NPTS; n += 256) {
            unsigned acc = 0;
            #pragma unroll
            for (int cq = 0; cq < 8; ++cq) {
                const uint4 pv = qp[(size_t)cq * NPTS + n];
                acc = sad8(pv.x, A[cq].x, acc);
                acc = sad8(pv.y, A[cq].y, acc);
                acc = sad8(pv.z, A[cq].z, acc);
                acc = sad8(pv.w, A[cq].w, acc);
            }
            sd[n] = (u16t)acc;
        }
        L = NPTS;
    }
    h[tid] = 0u;
    __syncthreads();

    // 2-level radix select for the exact kth value (d <= 32640 -> top byte < 128)
    for (int i = tid; i < L; i += 256) atomicAdd(&h[sd[i] >> 8], 1u);
    __syncthreads();
    if (tid == 0) {
        unsigned cum = 0, b = 0;
        for (;; ++b) { const unsigned c = h[b]; if (cum + c >= KSEL) break; cum += c; }
        s_b0 = b; s_r1 = KSEL - cum;
    }
    __syncthreads();
    const unsigned b0 = s_b0, r1 = s_r1;
    __syncthreads();
    h[tid] = 0u;
    __syncthreads();
    for (int i = tid; i < L; i += 256)
        if ((unsigned)(sd[i] >> 8) == b0) atomicAdd(&h[sd[i] & 255u], 1u);
    __syncthreads();
    if (tid == 0) {
        unsigned rem = r1, b = 0;
        for (;; ++b) { const unsigned c = h[b]; if (c >= rem) break; rem -= c; }
        s_kth = (b0 << 8) | b; s_remf = rem;
    }
    __syncthreads();
    const unsigned kth = s_kth, remf = s_remf;

    float local = 0.0f;
    for (int i = tid; i < L; i += 256) {
        const unsigned u = sd[i];
        if (u < kth) local += fmaxf(D - (float)u * dq, 0.0f);
    }
    red[tid] = local;
    __syncthreads();
    for (int s = 128; s >= 1; s >>= 1) { if (tid < s) red[tid] += red[tid + s]; __syncthreads(); }
    if (tid == 0) {
        const float total = red[0] + (float)remf * fmaxf(D - (float)kth * dq, 0.0f);
        atomicAdd(d_out, total * (1.0f / ((float)NA * (float)KSEL)));
    }
}

extern "C" void kernel_launch(void* const* d_in, const int* in_sizes, int n_in,
                              void* d_out, int out_size, void* d_ws, size_t ws_size,
                              hipStream_t stream) {
    const float* o1 = (const float*)d_in[0];
    const float* o2 = (const float*)d_in[1];
    const int*   a1 = (const int*)d_in[2];
    const int*   a2 = (const int*)d_in[3];
    float* out = (float*)d_out;

    // ws layout from 16B-aligned end:
    // [gmax 16B][tau 8KB][gcnt 8KB][astage 256KB][qp2 2.56MB][qp1 2.56MB];
    // candidate lists (u16, NTASK x CCAP = 8MB) at the base.
    const size_t qbytes = (size_t)NPTS * DIM;
    const size_t abytes = (size_t)NTASK * DIM;
    const uintptr_t end = ((uintptr_t)d_ws + ws_size) & ~(uintptr_t)15;
    unsigned* gmax   = (unsigned*)(end - 16);
    unsigned* tau    = (unsigned*)(end - 16 - (size_t)NTASK * 4);
    unsigned* gcnt   = (unsigned*)(end - 16 - (size_t)NTASK * 8);
    uint4*    astage = (uint4*)((uintptr_t)gcnt - abytes);
    uint4*    qp2    = (uint4*)((uintptr_t)astage - qbytes);
    uint4*    qp1    = (uint4*)((uintptr_t)qp2 - qbytes);
    u16t*     cand   = (u16t*)d_ws;

    init_kernel<<<(NTASK + 255) / 256, 256, 0, stream>>>(out, gcnt, gmax);
    maxabs_kernel<<<1024, 256, 0, stream>>>(o1, o2, gmax);
    quant_pack_kernel<<<2 * NPTS * 8 / 256, 256, 0, stream>>>(o1, o2, qp1, qp2, gmax);
    astage_kernel<<<(NTASK * 8 + 255) / 256, 256, 0, stream>>>(o1, o2, a1, a2, astage, gmax);
    sample_kernel<<<NTASK, 256, 0, stream>>>(qp1, qp2, astage, tau);

    dim3 gd(NTASK / G, (NPTS + TILE - 1) / TILE);
    dist_kernel<<<gd, 256, 0, stream>>>(qp1, qp2, astage, tau, cand, gcnt);
    finish_kernel<<<NTASK, 256, 0, stream>>>(o1, o2, a1, a2, qp1, qp2, astage,
                                             cand, gcnt, gmax, out);
}

// Round 8
// 182.988 us; speedup vs baseline: 1.7181x; 1.7181x over previous
//
#include <hip/hip_runtime.h>
#include <hip/hip_bf16.h>

#define NPTS  20000
#define DIM   128
#define NA    1024
#define NTASK 2048
#define G     8        // tasks per dist block
#define P     4        // points per thread (wave-strided)
#define TILE  1024     // points per dist block
#define NTILE 20       // NPTS / TILE (ceil)
#define SLOT  96       // candidate slots per (task, tile): mean 24, +15 sigma
#define KSEL  50
#define GAMMA 1.0f
#define RRANK 12       // sample rank used as threshold (of 512 samples)
#define LMAX  (NTILE * SLOT)   // 1920 max gathered candidates

typedef unsigned char  u8t;
typedef unsigned short u16t;

static __device__ __forceinline__ unsigned sad8(unsigned a, unsigned b, unsigned c) {
#if __has_builtin(__builtin_amdgcn_sad_u8)
    return __builtin_amdgcn_sad_u8(a, b, c);
#else
    unsigned d;
    asm("v_sad_u8 %0, %1, %2, %3" : "=v"(d) : "v"(a), "v"(b), "v"(c));
    return d;
#endif
}

__global__ void init_kernel(float* out, unsigned* gmax) {
    if (threadIdx.x == 0) { out[0] = 0.0f; gmax[0] = 0u; }
}

__global__ __launch_bounds__(256) void maxabs_kernel(
    const float* __restrict__ o1, const float* __restrict__ o2,
    unsigned* __restrict__ gmax)
{
    const int nt = (int)gridDim.x * 256;
    const float4* a = (const float4*)o1;
    const float4* b = (const float4*)o2;
    float m = 0.0f;
    for (int i = (int)blockIdx.x * 256 + (int)threadIdx.x; i < NPTS * DIM / 4; i += nt) {
        const float4 x = a[i], y = b[i];
        m = fmaxf(m, fmaxf(fmaxf(fabsf(x.x), fabsf(x.y)), fmaxf(fabsf(x.z), fabsf(x.w))));
        m = fmaxf(m, fmaxf(fmaxf(fabsf(y.x), fabsf(y.y)), fmaxf(fabsf(y.z), fabsf(y.w))));
    }
    #pragma unroll
    for (int off = 32; off >= 1; off >>= 1) m = fmaxf(m, __shfl_xor(m, off));
    if ((threadIdx.x & 63) == 0) atomicMax(gmax, __float_as_uint(m));  // m >= 0: bit order == float order
}

static __device__ __forceinline__ unsigned q4(const float4 v, const float M, const float s) {
    unsigned u0 = __float2uint_rn((v.x + M) * s); if (u0 > 255u) u0 = 255u;
    unsigned u1 = __float2uint_rn((v.y + M) * s); if (u1 > 255u) u1 = 255u;
    unsigned u2 = __float2uint_rn((v.z + M) * s); if (u2 > 255u) u2 = 255u;
    unsigned u3 = __float2uint_rn((v.w + M) * s); if (u3 > 255u) u3 = 255u;
    return u0 | (u1 << 8) | (u2 << 16) | (u3 << 24);
}

// Transpose-packed planes: qp[cq*NPTS + n] = dims 16cq..16cq+15 of point n.
// Consecutive idx -> cq fastest: lanes 0..7 read one row contiguously.
__global__ __launch_bounds__(256) void quant_pack_kernel(
    const float* __restrict__ o1, const float* __restrict__ o2,
    uint4* __restrict__ qp1, uint4* __restrict__ qp2,
    const unsigned* __restrict__ gmax)
{
    const float M = __uint_as_float(*gmax);
    const float s = 255.0f / (2.0f * M);
    const int idx = (int)blockIdx.x * 256 + (int)threadIdx.x;   // 1250*256 == 2*NPTS*8
    const int m  = idx / (NPTS * 8);
    const int r  = idx - m * (NPTS * 8);
    const int n  = r >> 3;
    const int cq = r & 7;
    const float4* src = (const float4*)((m ? o2 : o1) + (size_t)n * DIM + cq * 16);
    uint4 o;
    o.x = q4(src[0], M, s);
    o.y = q4(src[1], M, s);
    o.z = q4(src[2], M, s);
    o.w = q4(src[3], M, s);
    (m ? qp2 : qp1)[(size_t)cq * NPTS + n] = o;
}

// Gather + quantize anchor rows: astage[cq*NTASK + t].
__global__ __launch_bounds__(256) void astage_kernel(
    const float* __restrict__ o1, const float* __restrict__ o2,
    const int* __restrict__ anchor1, const int* __restrict__ anchor2,
    uint4* __restrict__ astage, const unsigned* __restrict__ gmax)
{
    const float M = __uint_as_float(*gmax);
    const float s = 255.0f / (2.0f * M);
    const int idx = (int)blockIdx.x * 256 + (int)threadIdx.x;
    if (idx >= NTASK * 8) return;
    const int t = idx >> 3, cq = idx & 7;
    int row; const float* src;
    if (t < NA) { row = anchor1[t];      src = o1; }
    else        { row = anchor2[t - NA]; src = o2; }
    const float4* rp = (const float4*)(src + (size_t)row * DIM + cq * 16);
    uint4 o;
    o.x = q4(rp[0], M, s);
    o.y = q4(rp[1], M, s);
    o.z = q4(rp[2], M, s);
    o.w = q4(rp[3], M, s);
    astage[(size_t)cq * NTASK + t] = o;
}

// Per-task threshold tau = exact rank-RRANK distance among 512 fixed samples
// (same 64KB of plane data for every block -> L2-hot).
__global__ __launch_bounds__(256) void sample_kernel(
    const uint4* __restrict__ qp1, const uint4* __restrict__ qp2,
    const uint4* __restrict__ astage, unsigned* __restrict__ tau)
{
    __shared__ u16t sd[512];
    __shared__ unsigned h[256];
    __shared__ unsigned s_b0, s_r1;

    const int tid = threadIdx.x;
    const int t = (int)blockIdx.x;
    const uint4* qp = (t < NA) ? qp2 : qp1;

    uint4 A[8];
    #pragma unroll
    for (int cq = 0; cq < 8; ++cq) A[cq] = astage[(size_t)cq * NTASK + t];

    for (int s = tid; s < 512; s += 256) {
        const int rr = s >> 6;
        const int n = rr * 2500 + (s & 63);
        unsigned acc = 0;
        #pragma unroll
        for (int cq = 0; cq < 8; ++cq) {
            const uint4 pv = qp[(size_t)cq * NPTS + n];
            acc = sad8(pv.x, A[cq].x, acc);
            acc = sad8(pv.y, A[cq].y, acc);
            acc = sad8(pv.z, A[cq].z, acc);
            acc = sad8(pv.w, A[cq].w, acc);
        }
        sd[s] = (u16t)acc;
    }
    h[tid] = 0u;
    __syncthreads();
    for (int s = tid; s < 512; s += 256) atomicAdd(&h[sd[s] >> 8], 1u);
    __syncthreads();
    if (tid == 0) {
        unsigned cum = 0, b = 0;
        for (;; ++b) { const unsigned c = h[b]; if (cum + c >= RRANK) break; cum += c; }
        s_b0 = b; s_r1 = RRANK - cum;
    }
    __syncthreads();
    const unsigned b0 = s_b0, r1 = s_r1;
    __syncthreads();
    h[tid] = 0u;
    __syncthreads();
    for (int s = tid; s < 512; s += 256)
        if ((unsigned)(sd[s] >> 8) == b0) atomicAdd(&h[sd[s] & 255u], 1u);
    __syncthreads();
    if (tid == 0) {
        unsigned rem = r1, b = 0;
        for (;; ++b) { const unsigned c = h[b]; if (c >= rem) break; rem -= c; }
        tau[t] = (b0 << 8) | b;
    }
}

// Main SAD pass. Emission: per-(task,tile) FIXED slots indexed by a per-task
// LDS counter -- no global atomics, no atomic-return waits (round 7's bug).
// Raw per-tile counts stored for exact overflow/undercount detection.
__global__ __launch_bounds__(256, 8) void dist_kernel(
    const uint4* __restrict__ qp1, const uint4* __restrict__ qp2,
    const uint4* __restrict__ astage, const unsigned* __restrict__ tau,
    u16t* __restrict__ cand, unsigned* __restrict__ bcnt)
{
    __shared__ unsigned scnt[G];

    const int tid = threadIdx.x;
    const int t0 = (int)blockIdx.x * G;
    const int tile = (int)blockIdx.y;
    const uint4* qp = (t0 < NA) ? qp2 : qp1;

    if (tid < G) scnt[tid] = 0u;

    const int w = tid >> 6, l = tid & 63;
    const int nbase = tile * TILE + w * 256 + l;   // point p: nbase + p*64

    unsigned acc[P][G];
    #pragma unroll
    for (int p = 0; p < P; ++p)
        #pragma unroll
        for (int g = 0; g < G; ++g) acc[p][g] = 0u;

    #pragma unroll
    for (int cq = 0; cq < 8; ++cq) {
        uint4 A[G];
        #pragma unroll
        for (int g = 0; g < G; ++g) A[g] = astage[(size_t)cq * NTASK + t0 + g];  // uniform -> s_load
        uint4 pv[P];
        #pragma unroll
        for (int p = 0; p < P; ++p) {
            int n = nbase + p * 64;
            n = n < NPTS ? n : NPTS - 1;       // clamped load; emission predicated
            pv[p] = qp[(size_t)cq * NPTS + n];
        }
        #pragma unroll
        for (int g = 0; g < G; ++g) {
            #pragma unroll
            for (int p = 0; p < P; ++p) {
                unsigned a = acc[p][g];
                a = sad8(pv[p].x, A[g].x, a);
                a = sad8(pv[p].y, A[g].y, a);
                a = sad8(pv[p].z, A[g].z, a);
                a = sad8(pv[p].w, A[g].w, a);
                acc[p][g] = a;
            }
        }
    }
    __syncthreads();   // scnt zeroing visible

    #pragma unroll
    for (int g = 0; g < G; ++g) {
        const unsigned tg = tau[t0 + g];       // uniform -> s_load
        u16t* cg = cand + (size_t)(t0 + g) * LMAX + tile * SLOT;
        #pragma unroll
        for (int p = 0; p < P; ++p) {
            const int n = nbase + p * 64;
            if (n < NPTS && acc[p][g] <= tg) {
                const unsigned idx = atomicAdd(&scnt[g], 1u);   // LDS, low traffic
                if (idx < SLOT) cg[idx] = (u16t)acc[p][g];      // fire-and-forget
            }
        }
    }
    __syncthreads();
    if (tid < G) bcnt[(size_t)(t0 + tid) * NTILE + tile] = scnt[tid];
}

// One block per task: gather ~470 candidates, exact 2-level radix for the
// 50th value, relu-sum. Fallback (undercount/slot overflow, P~1e-9):
// 3-pass streaming recompute -- exact, no big LDS.
__global__ __launch_bounds__(256) void finish_kernel(
    const float* __restrict__ o1, const float* __restrict__ o2,
    const int* __restrict__ anchor1, const int* __restrict__ anchor2,
    const uint4* __restrict__ qp1, const uint4* __restrict__ qp2,
    const uint4* __restrict__ astage,
    const u16t* __restrict__ cand, const unsigned* __restrict__ bcnt,
    const unsigned* __restrict__ gmax, float* __restrict__ d_out)
{
    __shared__ u16t sd[LMAX];
    __shared__ float red[256];
    __shared__ unsigned h[256];
    __shared__ unsigned offs[NTILE];
    __shared__ unsigned cnts[NTILE];
    __shared__ unsigned s_b0, s_r1, s_kth, s_remf, s_bad, s_total;

    const int tid = threadIdx.x;
    const int t = (int)blockIdx.x;

    // D = pos + GAMMA (exact fp32 from originals)
    const int a = (t < NA) ? t : (t - NA);
    const int i1 = anchor1[a], i2 = anchor2[a];
    float p = 0.0f;
    if (tid < DIM) p = fabsf(o1[(size_t)i1 * DIM + tid] - o2[(size_t)i2 * DIM + tid]);
    red[tid] = p;
    __syncthreads();
    for (int s = 128; s >= 1; s >>= 1) { if (tid < s) red[tid] += red[tid + s]; __syncthreads(); }
    const float D = red[0] + GAMMA;
    __syncthreads();

    const float M = __uint_as_float(*gmax);
    const float dq = 2.0f * M / 255.0f;

    if (tid < NTILE) cnts[tid] = bcnt[(size_t)t * NTILE + tid];
    __syncthreads();
    if (tid == 0) {
        unsigned off = 0, bad = 0;
        for (int i = 0; i < NTILE; ++i) {
            offs[i] = off;
            if (cnts[i] > SLOT) bad = 1;
            off += cnts[i];
        }
        s_total = off;
        s_bad = bad | (off < KSEL ? 1u : 0u);
    }
    __syncthreads();
    const unsigned total = s_total;

    float local = 0.0f;
    unsigned kth, remf;

    if (!s_bad) {
        // gather candidates into LDS
        for (int i = 0; i < NTILE; ++i)
            if (tid < (int)cnts[i]) sd[offs[i] + tid] = cand[(size_t)t * LMAX + i * SLOT + tid];
        h[tid] = 0u;
        __syncthreads();
        const int L = (int)total;
        for (int i = tid; i < L; i += 256) atomicAdd(&h[sd[i] >> 8], 1u);
        __syncthreads();
        if (tid == 0) {
            unsigned cum = 0, b = 0;
            for (;; ++b) { const unsigned c = h[b]; if (cum + c >= KSEL) break; cum += c; }
            s_b0 = b; s_r1 = KSEL - cum;
        }
        __syncthreads();
        const unsigned b0 = s_b0, r1 = s_r1;
        __syncthreads();
        h[tid] = 0u;
        __syncthreads();
        for (int i = tid; i < L; i += 256)
            if ((unsigned)(sd[i] >> 8) == b0) atomicAdd(&h[sd[i] & 255u], 1u);
        __syncthreads();
        if (tid == 0) {
            unsigned rem = r1, b = 0;
            for (;; ++b) { const unsigned c = h[b]; if (c >= rem) break; rem -= c; }
            s_kth = (b0 << 8) | b; s_remf = rem;
        }
        __syncthreads();
        kth = s_kth; remf = s_remf;
        for (int i = tid; i < L; i += 256) {
            const unsigned u = sd[i];
            if (u < kth) local += fmaxf(D - (float)u * dq, 0.0f);
        }
    } else {
        // exact streaming fallback: recompute row 3x (never taken in practice)
        const uint4* qp = (t < NA) ? qp2 : qp1;
        uint4 A[8];
        #pragma unroll
        for (int cq = 0; cq < 8; ++cq) A[cq] = astage[(size_t)cq * NTASK + t];
        h[tid] = 0u;
        __syncthreads();
        for (int n = tid; n < NPTS; n += 256) {
            unsigned acc = 0;
            #pragma unroll
            for (int cq = 0; cq < 8; ++cq) {
                const uint4 pv = qp[(size_t)cq * NPTS + n];
                acc = sad8(pv.x, A[cq].x, acc); acc = sad8(pv.y, A[cq].y, acc);
                acc = sad8(pv.z, A[cq].z, acc); acc = sad8(pv.w, A[cq].w, acc);
            }
            atomicAdd(&h[acc >> 8], 1u);
        }
        __syncthreads();
        if (tid == 0) {
            unsigned cum = 0, b = 0;
            for (;; ++b) { const unsigned c = h[b]; if (cum + c >= KSEL) break; cum += c; }
            s_b0 = b; s_r1 = KSEL - cum;
        }
        __syncthreads();
        const unsigned b0 = s_b0, r1 = s_r1;
        __syncthreads();
        h[tid] = 0u;
        __syncthreads();
        for (int n = tid; n < NPTS; n += 256) {
            unsigned acc = 0;
            #pragma unroll
            for (int cq = 0; cq < 8; ++cq) {
                const uint4 pv = qp[(size_t)cq * NPTS + n];
                acc = sad8(pv.x, A[cq].x, acc); acc = sad8(pv.y, A[cq].y, acc);
                acc = sad8(pv.z, A[cq].z, acc); acc = sad8(pv.w, A[cq].w, acc);
            }
            if ((acc >> 8) == b0) atomicAdd(&h[acc & 255u], 1u);
        }
        __syncthreads();
        if (tid == 0) {
            unsigned rem = r1, b = 0;
            for (;; ++b) { const unsigned c = h[b]; if (c >= rem) break; rem -= c; }
            s_kth = (b0 << 8) | b; s_remf = rem;
        }
        __syncthreads();
        kth = s_kth; remf = s_remf;
        for (int n = tid; n < NPTS; n += 256) {
            unsigned acc = 0;
            #pragma unroll
            for (int cq = 0; cq < 8; ++cq) {
                const uint4 pv = qp[(size_t)cq * NPTS + n];
                acc = sad8(pv.x, A[cq].x, acc); acc = sad8(pv.y, A[cq].y, acc);
                acc = sad8(pv.z, A[cq].z, acc); acc = sad8(pv.w, A[cq].w, acc);
            }
            if (acc < kth) local += fmaxf(D - (float)acc * dq, 0.0f);
        }
    }

    red[tid] = local;
    __syncthreads();
    for (int s = 128; s >= 1; s >>= 1) { if (tid < s) red[tid] += red[tid + s]; __syncthreads(); }
    if (tid == 0) {
        const float total_l = red[0] + (float)remf * fmaxf(D - (float)kth * dq, 0.0f);
        atomicAdd(d_out, total_l * (1.0f / ((float)NA * (float)KSEL)));
    }
}

extern "C" void kernel_launch(void* const* d_in, const int* in_sizes, int n_in,
                              void* d_out, int out_size, void* d_ws, size_t ws_size,
                              hipStream_t stream) {
    const float* o1 = (const float*)d_in[0];
    const float* o2 = (const float*)d_in[1];
    const int*   a1 = (const int*)d_in[2];
    const int*   a2 = (const int*)d_in[3];
    float* out = (float*)d_out;

    // ws layout from 16B-aligned end:
    // [gmax 16B][tau 8KB][bcnt 160KB][astage 256KB][qp2 2.56MB][qp1 2.56MB];
    // candidate slots (u16, NTASK x NTILE x SLOT = 7.86MB) at the base.
    const size_t qbytes = (size_t)NPTS * DIM;
    const size_t abytes = (size_t)NTASK * DIM;
    const uintptr_t end = ((uintptr_t)d_ws + ws_size) & ~(uintptr_t)15;
    unsigned* gmax   = (unsigned*)(end - 16);
    unsigned* tau    = (unsigned*)(end - 16 - (size_t)NTASK * 4);
    unsigned* bcnt   = (unsigned*)(end - 16 - (size_t)NTASK * 4 - (size_t)NTASK * NTILE * 4);
    uint4*    astage = (uint4*)((uintptr_t)bcnt - abytes);
    uint4*    qp2    = (uint4*)((uintptr_t)astage - qbytes);
    uint4*    qp1    = (uint4*)((uintptr_t)qp2 - qbytes);
    u16t*     cand   = (u16t*)d_ws;

    init_kernel<<<1, 64, 0, stream>>>(out, gmax);
    maxabs_kernel<<<1024, 256, 0, stream>>>(o1, o2, gmax);
    quant_pack_kernel<<<2 * NPTS * 8 / 256, 256, 0, stream>>>(o1, o2, qp1, qp2, gmax);
    astage_kernel<<<(NTASK * 8 + 255) / 256, 256, 0, stream>>>(o1, o2, a1, a2, astage, gmax);
    sample_kernel<<<NTASK, 256, 0, stream>>>(qp1, qp2, astage, tau);

    dim3 gd(NTASK / G, NTILE);
    dist_kernel<<<gd, 256, 0, stream>>>(qp1, qp2, astage, tau, cand, bcnt);
    finish_kernel<<<NTASK, 256, 0, stream>>>(o1, o2, a1, a2, qp1, qp2, astage,
                                             cand, bcnt, gmax, out);
}

// Round 9
// 127.576 us; speedup vs baseline: 2.4643x; 1.4343x over previous
//
#include <hip/hip_runtime.h>
#include <hip/hip_bf16.h>

#define NPTS  20000
#define DIM   128
#define NA    1024
#define NTASK 2048
#define G     8        // tasks per dist block
#define P     4        // points per thread (wave-strided)
#define TILE  1024     // points per dist block
#define NTILE 20       // ceil(NPTS / TILE)
#define NBX   (NTASK / G)          // 256 task-blocks
#define NWG   (NBX * NTILE)        // 5120 dist blocks (divisible by 8)
#define SLOT  96       // candidate slots per (task, tile): mean ~23, +15 sigma
#define KSEL  50
#define GAMMA 1.0f
#define RRANK 12       // sample rank used as threshold (of 512 samples)
#define LMAX  (NTILE * SLOT)   // 1920 slots per task
#define QBLK  (2 * NPTS * 8 / 256)  // 1250 quant blocks

typedef unsigned char  u8t;
typedef unsigned short u16t;

static __device__ __forceinline__ unsigned sad8(unsigned a, unsigned b, unsigned c) {
#if __has_builtin(__builtin_amdgcn_sad_u8)
    return __builtin_amdgcn_sad_u8(a, b, c);
#else
    unsigned d;
    asm("v_sad_u8 %0, %1, %2, %3" : "=v"(d) : "v"(a), "v"(b), "v"(c));
    return d;
#endif
}

// parallel select over a 256-bin LDS histogram: finds bin b with
// cum_before < target <= cum(b); writes b and (target - cum_before).
static __device__ __forceinline__ void scan_select(
    unsigned* h, unsigned* scn, unsigned target, int tid,
    unsigned* s_b, unsigned* s_r)
{
    scn[tid] = h[tid];
    __syncthreads();
    for (int off = 1; off < 256; off <<= 1) {
        const unsigned v = scn[tid];
        const unsigned u = (tid >= off) ? scn[tid - off] : 0u;
        __syncthreads();
        scn[tid] = v + u;
        __syncthreads();
    }
    const unsigned cumb = tid ? scn[tid - 1] : 0u;
    if (cumb < target && scn[tid] >= target) { *s_b = (unsigned)tid; *s_r = target - cumb; }
    __syncthreads();
}

__global__ void init_kernel(float* out, unsigned* gmax) {
    if (threadIdx.x == 0) { out[0] = 0.0f; gmax[0] = 0u; }
}

__global__ __launch_bounds__(256) void maxabs_kernel(
    const float* __restrict__ o1, const float* __restrict__ o2,
    unsigned* __restrict__ gmax)
{
    __shared__ float smax[4];
    const int nt = (int)gridDim.x * 256;
    const float4* a = (const float4*)o1;
    const float4* b = (const float4*)o2;
    float m = 0.0f;
    for (int i = (int)blockIdx.x * 256 + (int)threadIdx.x; i < NPTS * DIM / 4; i += nt) {
        const float4 x = a[i], y = b[i];
        m = fmaxf(m, fmaxf(fmaxf(fabsf(x.x), fabsf(x.y)), fmaxf(fabsf(x.z), fabsf(x.w))));
        m = fmaxf(m, fmaxf(fmaxf(fabsf(y.x), fabsf(y.y)), fmaxf(fabsf(y.z), fabsf(y.w))));
    }
    #pragma unroll
    for (int off = 32; off >= 1; off >>= 1) m = fmaxf(m, __shfl_xor(m, off));
    if ((threadIdx.x & 63) == 0) smax[threadIdx.x >> 6] = m;
    __syncthreads();
    if (threadIdx.x == 0) {
        m = fmaxf(fmaxf(smax[0], smax[1]), fmaxf(smax[2], smax[3]));
        atomicMax(gmax, __float_as_uint(m));   // one atomic per block; m>=0
    }
}

static __device__ __forceinline__ unsigned q4(const float4 v, const float M, const float s) {
    unsigned u0 = __float2uint_rn((v.x + M) * s); if (u0 > 255u) u0 = 255u;
    unsigned u1 = __float2uint_rn((v.y + M) * s); if (u1 > 255u) u1 = 255u;
    unsigned u2 = __float2uint_rn((v.z + M) * s); if (u2 > 255u) u2 = 255u;
    unsigned u3 = __float2uint_rn((v.w + M) * s); if (u3 > 255u) u3 = 255u;
    return u0 | (u1 << 8) | (u2 << 16) | (u3 << 24);
}

// Fused: blocks [0,QBLK) transpose-pack-quantize planes; the rest gather +
// quantize anchor rows into astage[cq*NTASK + t].
__global__ __launch_bounds__(256) void quant_astage_kernel(
    const float* __restrict__ o1, const float* __restrict__ o2,
    const int* __restrict__ anchor1, const int* __restrict__ anchor2,
    uint4* __restrict__ qp1, uint4* __restrict__ qp2,
    uint4* __restrict__ astage, const unsigned* __restrict__ gmax)
{
    const float M = __uint_as_float(*gmax);
    const float s = 255.0f / (2.0f * M);
    if ((int)blockIdx.x < QBLK) {
        const int idx = (int)blockIdx.x * 256 + (int)threadIdx.x;  // cq fastest
        const int m  = idx / (NPTS * 8);
        const int r  = idx - m * (NPTS * 8);
        const int n  = r >> 3;
        const int cq = r & 7;
        const float4* src = (const float4*)((m ? o2 : o1) + (size_t)n * DIM + cq * 16);
        uint4 o;
        o.x = q4(src[0], M, s);
        o.y = q4(src[1], M, s);
        o.z = q4(src[2], M, s);
        o.w = q4(src[3], M, s);
        (m ? qp2 : qp1)[(size_t)cq * NPTS + n] = o;
    } else {
        const int idx = ((int)blockIdx.x - QBLK) * 256 + (int)threadIdx.x;
        if (idx >= NTASK * 8) return;
        const int t = idx >> 3, cq = idx & 7;
        int row; const float* src;
        if (t < NA) { row = anchor1[t];      src = o1; }
        else        { row = anchor2[t - NA]; src = o2; }
        const float4* rp = (const float4*)(src + (size_t)row * DIM + cq * 16);
        uint4 o;
        o.x = q4(rp[0], M, s);
        o.y = q4(rp[1], M, s);
        o.z = q4(rp[2], M, s);
        o.w = q4(rp[3], M, s);
        astage[(size_t)cq * NTASK + t] = o;
    }
}

// Per-task threshold tau = exact rank-RRANK distance among 512 fixed samples.
// Sample values live in registers (2/thread); both selections are parallel.
__global__ __launch_bounds__(256) void sample_kernel(
    const uint4* __restrict__ qp1, const uint4* __restrict__ qp2,
    const uint4* __restrict__ astage, unsigned* __restrict__ tau)
{
    __shared__ unsigned h[256], scn[256];
    __shared__ unsigned s_b0, s_r1;

    const int tid = threadIdx.x;
    const int t = (int)blockIdx.x;
    const uint4* qp = (t < NA) ? qp2 : qp1;

    uint4 A[8];
    #pragma unroll
    for (int cq = 0; cq < 8; ++cq) A[cq] = astage[(size_t)cq * NTASK + t];

    unsigned d[2];
    #pragma unroll
    for (int k = 0; k < 2; ++k) {
        const int s = tid + k * 256;
        const int n = (s >> 6) * 2500 + (s & 63);
        unsigned acc = 0;
        #pragma unroll
        for (int cq = 0; cq < 8; ++cq) {
            const uint4 pv = qp[(size_t)cq * NPTS + n];
            acc = sad8(pv.x, A[cq].x, acc);
            acc = sad8(pv.y, A[cq].y, acc);
            acc = sad8(pv.z, A[cq].z, acc);
            acc = sad8(pv.w, A[cq].w, acc);
        }
        d[k] = acc;
    }
    h[tid] = 0u;
    __syncthreads();
    atomicAdd(&h[d[0] >> 8], 1u);
    atomicAdd(&h[d[1] >> 8], 1u);
    __syncthreads();
    scan_select(h, scn, RRANK, tid, &s_b0, &s_r1);
    const unsigned b0 = s_b0, r1 = s_r1;
    h[tid] = 0u;
    __syncthreads();
    if ((d[0] >> 8) == b0) atomicAdd(&h[d[0] & 255u], 1u);
    if ((d[1] >> 8) == b0) atomicAdd(&h[d[1] & 255u], 1u);
    __syncthreads();
    scan_select(h, scn, r1, tid, &s_b0, &s_r1);
    if (tid == (int)s_b0) tau[t] = (b0 << 8) | s_b0;   // exact rank-RRANK value
}

// Main SAD pass, XCD-swizzled tile-major so each XCD's working set (~2.5
// tiles x both matrices ~ 640KB + astage) stays L2-resident.
__global__ __launch_bounds__(256, 8) void dist_kernel(
    const uint4* __restrict__ qp1, const uint4* __restrict__ qp2,
    const uint4* __restrict__ astage, const unsigned* __restrict__ tau,
    u16t* __restrict__ cand, unsigned* __restrict__ bcnt)
{
    __shared__ unsigned scnt[G];

    const int tid = threadIdx.x;
    const int bid = (int)blockIdx.x;
    const int swz = (bid & 7) * (NWG / 8) + (bid >> 3);   // bijective: NWG%8==0
    const int tile = swz / NBX;                           // tile-major chunks
    const int bx   = swz - tile * NBX;
    const int t0 = bx * G;
    const uint4* qp = (t0 < NA) ? qp2 : qp1;

    if (tid < G) scnt[tid] = 0u;

    const int w = tid >> 6, l = tid & 63;
    const int nbase = tile * TILE + w * 256 + l;   // point p: nbase + p*64

    unsigned acc[P][G];
    #pragma unroll
    for (int p = 0; p < P; ++p)
        #pragma unroll
        for (int g = 0; g < G; ++g) acc[p][g] = 0u;

    #pragma unroll
    for (int cq = 0; cq < 8; ++cq) {
        uint4 A[G];
        #pragma unroll
        for (int g = 0; g < G; ++g) A[g] = astage[(size_t)cq * NTASK + t0 + g];  // uniform -> s_load
        uint4 pv[P];
        #pragma unroll
        for (int p = 0; p < P; ++p) {
            int n = nbase + p * 64;
            n = n < NPTS ? n : NPTS - 1;       // clamped load; emission predicated
            pv[p] = qp[(size_t)cq * NPTS + n];
        }
        #pragma unroll
        for (int g = 0; g < G; ++g) {
            #pragma unroll
            for (int p = 0; p < P; ++p) {
                unsigned a = acc[p][g];
                a = sad8(pv[p].x, A[g].x, a);
                a = sad8(pv[p].y, A[g].y, a);
                a = sad8(pv[p].z, A[g].z, a);
                a = sad8(pv[p].w, A[g].w, a);
                acc[p][g] = a;
            }
        }
    }
    __syncthreads();   // scnt zeroing visible

    #pragma unroll
    for (int g = 0; g < G; ++g) {
        const unsigned tg = tau[t0 + g];       // uniform -> s_load
        u16t* cg = cand + (size_t)(t0 + g) * LMAX + tile * SLOT;
        #pragma unroll
        for (int p = 0; p < P; ++p) {
            const int n = nbase + p * 64;
            if (n < NPTS && acc[p][g] <= tg) {
                const unsigned idx = atomicAdd(&scnt[g], 1u);   // LDS, low traffic
                if (idx < SLOT) cg[idx] = (u16t)acc[p][g];      // fire-and-forget
            }
        }
    }
    __syncthreads();
    if (tid < G) bcnt[(size_t)(t0 + tid) * NTILE + tile] = scnt[tid];
}

// One block per task: slots -> registers (8/thread, 0xFFFF sentinel for
// empties), two parallel radix selections, relu-sum from registers.
// Fallback (slot overflow / undercount): exact 3-pass streaming recompute.
__global__ __launch_bounds__(256) void finish_kernel(
    const float* __restrict__ o1, const float* __restrict__ o2,
    const int* __restrict__ anchor1, const int* __restrict__ anchor2,
    const uint4* __restrict__ qp1, const uint4* __restrict__ qp2,
    const uint4* __restrict__ astage,
    const u16t* __restrict__ cand, const unsigned* __restrict__ bcnt,
    const unsigned* __restrict__ gmax, float* __restrict__ d_out)
{
    __shared__ float red[256];
    __shared__ unsigned h[256], scn[256];
    __shared__ unsigned cnts[NTILE];
    __shared__ unsigned s_b0, s_r1, s_bad;

    const int tid = threadIdx.x;
    const int t = (int)blockIdx.x;

    // D = pos + GAMMA (exact fp32 from originals)
    const int a = (t < NA) ? t : (t - NA);
    const int i1 = anchor1[a], i2 = anchor2[a];
    float p = 0.0f;
    if (tid < DIM) p = fabsf(o1[(size_t)i1 * DIM + tid] - o2[(size_t)i2 * DIM + tid]);
    red[tid] = p;
    __syncthreads();
    for (int s = 128; s >= 1; s >>= 1) { if (tid < s) red[tid] += red[tid + s]; __syncthreads(); }
    const float D = red[0] + GAMMA;
    __syncthreads();

    const float M = __uint_as_float(*gmax);
    const float dq = 2.0f * M / 255.0f;

    if (tid < NTILE) cnts[tid] = bcnt[(size_t)t * NTILE + tid];
    __syncthreads();
    if (tid == 0) {
        unsigned total = 0, bad = 0;
        for (int i = 0; i < NTILE; ++i) { if (cnts[i] > SLOT) bad = 1; total += cnts[i]; }
        s_bad = bad | (total < KSEL ? 1u : 0u);
    }
    h[tid] = 0u;
    __syncthreads();

    float local = 0.0f;
    unsigned kth, remf;

    if (!s_bad) {
        unsigned val[8];
        #pragma unroll
        for (int k = 0; k < 8; ++k) {
            const int idx = tid + k * 256;
            unsigned v = 0xFFFFu;
            if (idx < LMAX) {
                const int tile = idx / SLOT;
                const int j = idx - tile * SLOT;
                if ((unsigned)j < cnts[tile]) v = cand[(size_t)t * LMAX + idx];
            }
            val[k] = v;
            if (v != 0xFFFFu) atomicAdd(&h[v >> 8], 1u);
        }
        __syncthreads();
        scan_select(h, scn, KSEL, tid, &s_b0, &s_r1);   // sentinels in bin 255, b0<128
        const unsigned b0 = s_b0, r1 = s_r1;
        h[tid] = 0u;
        __syncthreads();
        #pragma unroll
        for (int k = 0; k < 8; ++k)
            if ((val[k] >> 8) == b0) atomicAdd(&h[val[k] & 255u], 1u);
        __syncthreads();
        scan_select(h, scn, r1, tid, &s_b0, &s_r1);
        kth = (b0 << 8) | s_b0;
        remf = s_r1;
        #pragma unroll
        for (int k = 0; k < 8; ++k) {
            const unsigned u = val[k];             // sentinel 0xFFFF never < kth
            if (u < kth) local += fmaxf(D - (float)u * dq, 0.0f);
        }
    } else {
        // exact streaming fallback (never taken in practice)
        const uint4* qp = (t < NA) ? qp2 : qp1;
        uint4 A[8];
        #pragma unroll
        for (int cq = 0; cq < 8; ++cq) A[cq] = astage[(size_t)cq * NTASK + t];
        for (int n = tid; n < NPTS; n += 256) {
            unsigned acc = 0;
            #pragma unroll
            for (int cq = 0; cq < 8; ++cq) {
                const uint4 pv = qp[(size_t)cq * NPTS + n];
                acc = sad8(pv.x, A[cq].x, acc); acc = sad8(pv.y, A[cq].y, acc);
                acc = sad8(pv.z, A[cq].z, acc); acc = sad8(pv.w, A[cq].w, acc);
            }
            atomicAdd(&h[acc >> 8], 1u);
        }
        __syncthreads();
        scan_select(h, scn, KSEL, tid, &s_b0, &s_r1);
        const unsigned b0 = s_b0, r1 = s_r1;
        h[tid] = 0u;
        __syncthreads();
        for (int n = tid; n < NPTS; n += 256) {
            unsigned acc = 0;
            #pragma unroll
            for (int cq = 0; cq < 8; ++cq) {
                const uint4 pv = qp[(size_t)cq * NPTS + n];
                acc = sad8(pv.x, A[cq].x, acc); acc = sad8(pv.y, A[cq].y, acc);
                acc = sad8(pv.z, A[cq].z, acc); acc = sad8(pv.w, A[cq].w, acc);
            }
            if ((acc >> 8) == b0) atomicAdd(&h[acc & 255u], 1u);
        }
        __syncthreads();
        scan_select(h, scn, r1, tid, &s_b0, &s_r1);
        kth = (b0 << 8) | s_b0;
        remf = s_r1;
        for (int n = tid; n < NPTS; n += 256) {
            unsigned acc = 0;
            #pragma unroll
            for (int cq = 0; cq < 8; ++cq) {
                const uint4 pv = qp[(size_t)cq * NPTS + n];
                acc = sad8(pv.x, A[cq].x, acc); acc = sad8(pv.y, A[cq].y, acc);
                acc = sad8(pv.z, A[cq].z, acc); acc = sad8(pv.w, A[cq].w, acc);
            }
            if (acc < kth) local += fmaxf(D - (float)acc * dq, 0.0f);
        }
    }

    red[tid] = local;
    __syncthreads();
    for (int s = 128; s >= 1; s >>= 1) { if (tid < s) red[tid] += red[tid + s]; __syncthreads(); }
    if (tid == 0) {
        const float total_l = red[0] + (float)remf * fmaxf(D - (float)kth * dq, 0.0f);
        atomicAdd(d_out, total_l * (1.0f / ((float)NA * (float)KSEL)));
    }
}

extern "C" void kernel_launch(void* const* d_in, const int* in_sizes, int n_in,
                              void* d_out, int out_size, void* d_ws, size_t ws_size,
                              hipStream_t stream) {
    const float* o1 = (const float*)d_in[0];
    const float* o2 = (const float*)d_in[1];
    const int*   a1 = (const int*)d_in[2];
    const int*   a2 = (const int*)d_in[3];
    float* out = (float*)d_out;

    // ws layout from 16B-aligned end:
    // [gmax 16B][tau 8KB][bcnt 160KB][astage 256KB][qp2 2.56MB][qp1 2.56MB];
    // candidate slots (u16, NTASK x LMAX = 7.86MB) at the base.
    const size_t qbytes = (size_t)NPTS * DIM;
    const size_t abytes = (size_t)NTASK * DIM;
    const uintptr_t end = ((uintptr_t)d_ws + ws_size) & ~(uintptr_t)15;
    unsigned* gmax   = (unsigned*)(end - 16);
    unsigned* tau    = (unsigned*)(end - 16 - (size_t)NTASK * 4);
    unsigned* bcnt   = (unsigned*)(end - 16 - (size_t)NTASK * 4 - (size_t)NTASK * NTILE * 4);
    uint4*    astage = (uint4*)((uintptr_t)bcnt - abytes);
    uint4*    qp2    = (uint4*)((uintptr_t)astage - qbytes);
    uint4*    qp1    = (uint4*)((uintptr_t)qp2 - qbytes);
    u16t*     cand   = (u16t*)d_ws;

    init_kernel<<<1, 64, 0, stream>>>(out, gmax);
    maxabs_kernel<<<512, 256, 0, stream>>>(o1, o2, gmax);
    quant_astage_kernel<<<QBLK + (NTASK * 8 + 255) / 256, 256, 0, stream>>>(
        o1, o2, a1, a2, qp1, qp2, astage, gmax);
    sample_kernel<<<NTASK, 256, 0, stream>>>(qp1, qp2, astage, tau);
    dist_kernel<<<NWG, 256, 0, stream>>>(qp1, qp2, astage, tau, cand, bcnt);
    finish_kernel<<<NTASK, 256, 0, stream>>>(o1, o2, a1, a2, qp1, qp2, astage,
                                             cand, bcnt, gmax, out);
}